// Round 1
// baseline (162.932 us; speedup 1.0000x reference)
//
#include <hip/hip_runtime.h>
#include <math.h>

#define NPG 500      // nodes per graph
#define DIM 256      // feature dim
#define HID 64       // hidden dim
#define RATIO_NORM 600.0f

// ---------------------------------------------------------------- K1: scores
// score[n] = relu(x[n,:] @ Ws1 + bs1) @ Ws2 + bs2
// One thread per node; acc[64] in VGPRs; weight addresses are wave-uniform so
// they compile to scalar loads (SGPR operand to v_fma -> no vector-mem cost).
__global__ __launch_bounds__(256) void k_score(
    const float* __restrict__ x,
    const float* __restrict__ Ws1,   // [DIM][HID] row-major
    const float* __restrict__ bs1,   // [HID]
    const float* __restrict__ Ws2,   // [HID]
    const float* __restrict__ bs2,   // [1]
    float* __restrict__ score, int N)
{
    int node = blockIdx.x * 256 + threadIdx.x;
    int nodec = node < N ? node : (N - 1);           // clamp, guard store below
    const float4* xr = reinterpret_cast<const float4*>(x + (size_t)nodec * DIM);

    float acc[HID];
#pragma unroll
    for (int h = 0; h < HID; ++h) acc[h] = bs1[h];

    for (int k4 = 0; k4 < DIM / 4; ++k4) {
        float4 xv = xr[k4];
        const float* w = Ws1 + (size_t)(k4 * 4) * HID;
#pragma unroll
        for (int h = 0; h < HID; ++h) {
            acc[h] = fmaf(xv.x, w[h],           acc[h]);
            acc[h] = fmaf(xv.y, w[HID + h],     acc[h]);
            acc[h] = fmaf(xv.z, w[2 * HID + h], acc[h]);
            acc[h] = fmaf(xv.w, w[3 * HID + h], acc[h]);
        }
    }
    float sc = bs2[0];
#pragma unroll
    for (int h = 0; h < HID; ++h)
        sc = fmaf(fmaxf(acc[h], 0.0f), Ws2[h], sc);
    if (node < N) score[node] = sc;
}

// ------------------------------------------------------------- K2: edge count
// counts[g] = #edges with src/NPG == dst/NPG == g
__global__ __launch_bounds__(256) void k_edges(
    const int* __restrict__ esrc, const int* __restrict__ edst,
    int* __restrict__ counts, int E, int G)
{
    __shared__ int hist[256];
    for (int i = threadIdx.x; i < G; i += 256) hist[i] = 0;
    __syncthreads();

    int nchunk = E >> 2;
    const int4* s4 = reinterpret_cast<const int4*>(esrc);
    const int4* d4 = reinterpret_cast<const int4*>(edst);
    for (int c = blockIdx.x * 256 + threadIdx.x; c < nchunk; c += gridDim.x * 256) {
        int4 s = s4[c], d = d4[c];
        int g;
        g = s.x / NPG; if (g == d.x / NPG) atomicAdd(&hist[g], 1);
        g = s.y / NPG; if (g == d.y / NPG) atomicAdd(&hist[g], 1);
        g = s.z / NPG; if (g == d.z / NPG) atomicAdd(&hist[g], 1);
        g = s.w / NPG; if (g == d.w / NPG) atomicAdd(&hist[g], 1);
    }
    if (blockIdx.x == 0) {  // scalar tail (E not multiple of 4)
        for (int e = (nchunk << 2) + threadIdx.x; e < E; e += 256) {
            int g = esrc[e] / NPG;
            if (g == edst[e] / NPG) atomicAdd(&hist[g], 1);
        }
    }
    __syncthreads();
    for (int i = threadIdx.x; i < G; i += 256)
        if (hist[i]) atomicAdd(&counts[i], hist[i]);
}

// ------------------------------------------- K3: per-graph avg + keep_num MLP
__global__ __launch_bounds__(256) void k_keep(
    const float* __restrict__ score,
    const int* __restrict__ counts,
    const float* __restrict__ Wp1,   // [3][HID]
    const float* __restrict__ bp1,   // [HID]
    const float* __restrict__ Wp2,   // [HID]
    const float* __restrict__ bp2,   // [1]
    int* __restrict__ keep_num)
{
    int g = blockIdx.x;
    __shared__ float red[256];
    const float* s = score + (size_t)g * NPG;
    float v = 0.0f;
    for (int i = threadIdx.x; i < NPG; i += 256) v += s[i];
    red[threadIdx.x] = v;
    __syncthreads();
    for (int off = 128; off >= 1; off >>= 1) {
        if (threadIdx.x < off) red[threadIdx.x] += red[threadIdx.x + off];
        __syncthreads();
    }
    if (threadIdx.x < 64) {
        float f0 = (float)NPG / RATIO_NORM;
        float f1 = red[0] / (float)NPG;                    // avg score
        float f2 = (float)counts[g] / (float)(NPG * (NPG - 1));  // density
        int h = threadIdx.x;
        float hv = bp1[h];
        hv = fmaf(f0, Wp1[h], hv);
        hv = fmaf(f1, Wp1[HID + h], hv);
        hv = fmaf(f2, Wp1[2 * HID + h], hv);
        hv = fmaxf(hv, 0.0f) * Wp2[h];
#pragma unroll
        for (int m = 32; m >= 1; m >>= 1) hv += __shfl_xor(hv, m, 64);
        if (h == 0) {
            float z = hv + bp2[0];
            float kr = 1.0f / (1.0f + expf(-z));
            int kn = (int)((float)NPG * kr);               // trunc, matches astype(int32)
            keep_num[g] = kn < 2 ? 2 : kn;
        }
    }
}

// --------------------------------- K4: per-graph rank -> mask -> gated output
__global__ __launch_bounds__(256) void k_mask_out(
    const float* __restrict__ x,
    const float* __restrict__ score,
    const int* __restrict__ keep_num,
    float* __restrict__ out_x,      // [N*DIM]
    float* __restrict__ out_mask)   // [N] as 0.0/1.0
{
    int g = blockIdx.x;
    __shared__ float s[NPG];
    __shared__ float gate[NPG];
    const float* sg = score + (size_t)g * NPG;
    for (int i = threadIdx.x; i < NPG; i += 256) s[i] = sg[i];
    __syncthreads();

    int kn = keep_num[g];
    // rank = #{j: s_j > s_i} + #{j<i: s_j == s_i}  (== position under stable
    // argsort of -s); keep iff rank < kn
    for (int i = threadIdx.x; i < NPG; i += 256) {
        float si = s[i];
        int rank = 0;
        for (int j = 0; j < NPG; ++j) {
            float sj = s[j];
            rank += (sj > si) || ((sj == si) && (j < i));
        }
        bool keep = rank < kn;
        out_mask[(size_t)g * NPG + i] = keep ? 1.0f : 0.0f;
        gate[i] = keep ? tanhf(si) : 0.0f;
    }
    __syncthreads();

    // write rows: 4 rows in flight, 64 lanes x float4 per row (coalesced 1KB)
    int lane = threadIdx.x & 63;
    int wrow = threadIdx.x >> 6;
    for (int r = wrow; r < NPG; r += 4) {
        float gt = gate[r];
        size_t base = ((size_t)g * NPG + r) * DIM;
        float4* o = reinterpret_cast<float4*>(out_x + base);
        if (gt != 0.0f) {
            const float4* xi = reinterpret_cast<const float4*>(x + base);
            float4 v = xi[lane];
            o[lane] = make_float4(v.x * gt, v.y * gt, v.z * gt, v.w * gt);
        } else {
            o[lane] = make_float4(0.0f, 0.0f, 0.0f, 0.0f);
        }
    }
}

// ---------------------------------------------------------------------- host
extern "C" void kernel_launch(void* const* d_in, const int* in_sizes, int n_in,
                              void* d_out, int out_size, void* d_ws, size_t ws_size,
                              hipStream_t stream)
{
    const float* x   = (const float*)d_in[0];
    const float* Ws1 = (const float*)d_in[1];
    const float* bs1 = (const float*)d_in[2];
    const float* Ws2 = (const float*)d_in[3];
    const float* bs2 = (const float*)d_in[4];
    const float* Wp1 = (const float*)d_in[5];
    const float* bp1 = (const float*)d_in[6];
    const float* Wp2 = (const float*)d_in[7];
    const float* bp2 = (const float*)d_in[8];
    const int* esrc  = (const int*)d_in[9];
    const int* edst  = (const int*)d_in[10];

    int E = in_sizes[9];
    int N = in_sizes[0] / DIM;
    int G = N / NPG;

    float* score  = (float*)d_ws;                       // N floats
    int* counts   = (int*)((char*)d_ws + (size_t)N * sizeof(float)); // G ints
    int* keep     = counts + G;                          // G ints

    float* out_x    = (float*)d_out;
    float* out_mask = out_x + (size_t)N * DIM;

    hipMemsetAsync(counts, 0, G * sizeof(int), stream);
    k_score<<<(N + 255) / 256, 256, 0, stream>>>(x, Ws1, bs1, Ws2, bs2, score, N);
    k_edges<<<512, 256, 0, stream>>>(esrc, edst, counts, E, G);
    k_keep<<<G, 256, 0, stream>>>(score, counts, Wp1, bp1, Wp2, bp2, keep);
    k_mask_out<<<G, 256, 0, stream>>>(x, score, keep, out_x, out_mask);
}